// Round 4
// baseline (425.208 us; speedup 1.0000x reference)
//
#include <hip/hip_runtime.h>

typedef float f32x4 __attribute__((ext_vector_type(4)));
typedef short s16x8 __attribute__((ext_vector_type(8)));
typedef unsigned short u16;

__device__ __forceinline__ u16 f2bf(float f) {
    union { float f; unsigned u; } v; v.f = f;
    return (u16)((v.u + 0x7fffu + ((v.u >> 16) & 1u)) >> 16);
}
__device__ __forceinline__ float bf2f(u16 h) {
    union { unsigned u; float f; } v; v.u = ((unsigned)h) << 16;
    return v.f;
}
__device__ __forceinline__ float fast_exp2(float x) {
#if __has_builtin(__builtin_amdgcn_exp2f)
    return __builtin_amdgcn_exp2f(x);
#else
    return exp2f(x);
#endif
}

// async global->LDS, 16B/lane; LDS dest = wave-uniform base + lane*16 [m97/m104]
__device__ __forceinline__ void gload_lds16(const void* g, void* l) {
    __builtin_amdgcn_global_load_lds((__attribute__((address_space(1))) void*)g,
                                     (__attribute__((address_space(3))) void*)l, 16, 0, 0);
}

// Mega convert: x (1048576 units) -> xb, then wq|wk|wv (524288+131072+131072) -> wqkvb
// contiguous. 1 unit = 8 elems. Grid exactly 7168 blocks x 256.
__global__ __launch_bounds__(256) void cvt_all(const float* __restrict__ x,  const float* __restrict__ wq,
                                               const float* __restrict__ wk, const float* __restrict__ wv,
                                               u16* __restrict__ xb, u16* __restrict__ wqkvb) {
    int u = blockIdx.x * 256 + threadIdx.x;
    const float* src;
    u16* dst;
    if (u < 1048576) { src = x + (size_t)u * 8; dst = xb + (size_t)u * 8; }
    else {
        int w = u - 1048576;
        dst = wqkvb + (size_t)w * 8;
        if (w < 524288)      src = wq + (size_t)w * 8;
        else if (w < 655360) src = wk + (size_t)(w - 524288) * 8;
        else                 src = wv + (size_t)(w - 655360) * 8;
    }
    const float4* p = (const float4*)src;
    float4 a = p[0], b = p[1];
    s16x8 o;
    o[0] = f2bf(a.x); o[1] = f2bf(a.y); o[2] = f2bf(a.z); o[3] = f2bf(a.w);
    o[4] = f2bf(b.x); o[5] = f2bf(b.y); o[6] = f2bf(b.z); o[7] = f2bf(b.w);
    *(s16x8*)dst = o;
}

// fp32 -> bf16 elementwise (for wo after wqkv region is free)
__global__ __launch_bounds__(256) void cvt_kernel(const float* __restrict__ in,
                                                  u16* __restrict__ out, int n8) {
    int i = blockIdx.x * 256 + threadIdx.x;
    if (i >= n8) return;
    const float4* p = (const float4*)(in + (size_t)i * 8);
    float4 a = p[0], b = p[1];
    s16x8 o;
    o[0] = f2bf(a.x); o[1] = f2bf(a.y); o[2] = f2bf(a.z); o[3] = f2bf(a.w);
    o[4] = f2bf(b.x); o[5] = f2bf(b.y); o[6] = f2bf(b.z); o[7] = f2bf(b.w);
    *(s16x8*)(out + (size_t)i * 8) = o;
}

// C = A[M,K] @ B[N,K]^T, bf16 in. 128x128 tile, BK=64, global_load_lds staging,
// XOR-swizzled LDS. OUT=1: fp32 C[M,N]. OUT=4: fused qkv routing:
//   n<2048 -> bf16 Cq[m*2048+n]; 2048<=n<2560 -> bf16 Ck[m*512+(n-2048)];
//   n>=2560 -> bf16 transposed Cv[(n-2560)*M + m]
template<int OUT>
__global__ __launch_bounds__(256) void gemm128(const u16* __restrict__ A, const u16* __restrict__ B,
                                               void* __restrict__ C, void* __restrict__ Ck,
                                               void* __restrict__ Cv, int M, int N, int K) {
    __shared__ __align__(16) u16 Ald[128 * 64];
    __shared__ __align__(16) u16 Bld[128 * 64];
    const int t = threadIdx.x, wid = t >> 6, lane = t & 63;
    const int m0 = blockIdx.y * 128, n0 = blockIdx.x * 128;
    const int ml = lane & 15, quad = lane >> 4, m7 = ml & 7;
    const int wm = (wid & 1) * 64, wn = (wid >> 1) * 64;
    const int sr = lane >> 3, sc = lane & 7;

    f32x4 acc[4][4] = {};

    for (int k0 = 0; k0 < K; k0 += 64) {
        if (k0) __syncthreads();
        #pragma unroll
        for (int i = 0; i < 4; ++i) {
            int seg = wid * 4 + i;
            int r = seg * 8 + sr;
            int c = (sc ^ (r & 7)) * 8;
            gload_lds16(A + (size_t)(m0 + r) * K + k0 + c, &Ald[seg * 512]);
            gload_lds16(B + (size_t)(n0 + r) * K + k0 + c, &Bld[seg * 512]);
        }
        __syncthreads();
        #pragma unroll
        for (int kk = 0; kk < 64; kk += 32) {
            s16x8 af[4], bf[4];
            #pragma unroll
            for (int mi = 0; mi < 4; ++mi)
                af[mi] = *(const s16x8*)&Ald[(wm + mi * 16 + ml) * 64 + (((kk >> 3) + quad) ^ m7) * 8];
            #pragma unroll
            for (int ni = 0; ni < 4; ++ni)
                bf[ni] = *(const s16x8*)&Bld[(wn + ni * 16 + ml) * 64 + (((kk >> 3) + quad) ^ m7) * 8];
            #pragma unroll
            for (int mi = 0; mi < 4; ++mi)
                #pragma unroll
                for (int ni = 0; ni < 4; ++ni)
                    acc[mi][ni] = __builtin_amdgcn_mfma_f32_16x16x32_bf16(af[mi], bf[ni], acc[mi][ni], 0, 0, 0);
        }
    }
    // C/D layout: col=lane&15, row=quad*4+reg [m89/m91]
    #pragma unroll
    for (int mi = 0; mi < 4; ++mi)
        #pragma unroll
        for (int ni = 0; ni < 4; ++ni) {
            int gmb = m0 + wm + mi * 16 + quad * 4;
            int gn  = n0 + wn + ni * 16 + ml;
            if constexpr (OUT == 4) {
                if (n0 < 2048) {
                    #pragma unroll
                    for (int r = 0; r < 4; ++r)
                        ((u16*)C)[(size_t)(gmb + r) * 2048 + gn] = f2bf(acc[mi][ni][r]);
                } else if (n0 < 2560) {
                    #pragma unroll
                    for (int r = 0; r < 4; ++r)
                        ((u16*)Ck)[(size_t)(gmb + r) * 512 + (gn - 2048)] = f2bf(acc[mi][ni][r]);
                } else {
                    ushort4 v;
                    v.x = f2bf(acc[mi][ni][0]); v.y = f2bf(acc[mi][ni][1]);
                    v.z = f2bf(acc[mi][ni][2]); v.w = f2bf(acc[mi][ni][3]);
                    *(ushort4*)((u16*)Cv + (size_t)(gn - 2560) * M + gmb) = v;
                }
            } else {
                #pragma unroll
                for (int r = 0; r < 4; ++r)
                    ((float*)C)[(size_t)(gmb + r) * N + gn] = acc[mi][ni][r];
            }
        }
}

// Fused NeoX RoPE for q (16 heads, scaled) + k (4 heads). pos = tok % 2048.
// q pre-scaled by 1/sqrt(128)*log2(e) -> attention works in the log2 domain.
__global__ __launch_bounds__(256) void rope_kernel(u16* __restrict__ qb, u16* __restrict__ kb,
                                                   int nq, int ntot, float sq) {
    int idx = blockIdx.x * 256 + threadIdx.x;
    if (idx >= ntot) return;
    u16* base; int nheads; float scl; int id;
    if (idx < nq) { base = qb; nheads = 16; scl = sq;  id = idx; }
    else          { base = kb; nheads = 4;  scl = 1.f; id = idx - nq; }
    int i = id & 63;
    int rest = id >> 6;
    int hh = rest % nheads;
    int tok = rest / nheads;
    int tpos = tok & 2047;
    u16* row = base + (size_t)tok * nheads * 128 + hh * 128;
    float x1 = bf2f(row[i]);
    float x2 = bf2f(row[i + 64]);
    float inv = expf(-(float)i * 0.14391156731570787f); // 10000^(-i/64)
    float ang = (float)tpos * inv;
    float s, c;
    sincosf(ang, &s, &c);
    row[i]      = f2bf((x1 * c - x2 * s) * scl);
    row[i + 64] = f2bf((x2 * c + x1 * s) * scl);
}

// Flash attention v4: BARRIER-FREE. Evidence: v2 (dbuf prefetch) neutral, v3
// (more blocks) gained only via TLP -> the barrier-coupled staging chain is the
// bottleneck. K/V fragment addresses are HEAD-INDEPENDENT: the 4 waves (4 q-heads
// of one kv group) read identical K/V bytes, so LDS staging buys nothing that
// L1 doesn't -> read kf/vf DIRECTLY from global (contiguous 16B/lane; verified
// identical to post-XOR staged layout). No __syncthreads anywhere; waves fully
// independent. Pair-in-wave (qa=u, qb=127-u) halves fragment traffic (each
// kf/vf feeds up to 4 MFMAs) and makes durations near-uniform (17..32 iters).
// XCD pinning: bid&7 selects (kv,b) group -> its 1MB K/V working set stays in
// one XCD's 4MB L2. LDS = 16KB (P transpose only, per-wave private, lgkmcnt-
// ordered). Causal mask only on each tile's diagonal iteration.
__global__ __launch_bounds__(256, 2) void attn_kernel(const u16* __restrict__ Q, const u16* __restrict__ Kb,
                                                      const u16* __restrict__ Vt, u16* __restrict__ O) {
    __shared__ __align__(16) u16 Plds[4][2][16 * 64];  // 16KB (2 tiles per wave)
    const int t = threadIdx.x, wslot = t >> 6, lane = t & 63;
    const int bid = blockIdx.x;          // 512 blocks, 1D
    const int g = bid & 7;               // XCD pin: group (kv,b) -> XCD g
    const int u = bid >> 3;              // pair index 0..63
    const int kv = g & 3, b = g >> 2;
    const int qa = u, qb = 127 - u;
    const int h = kv * 4 + wslot;
    const int ml = lane & 15, quad = lane >> 4, m7 = ml & 7;
    const int t0a = qa * 16, t0b = qb * 16;
    const int na = (qa >> 2) + 1;        // 1..16
    const int nb = (qb >> 2) + 1;        // 17..32 (always > na)

    // Q fragments: A layout m=lane&15, k=quad*8+j [m120]
    s16x8 qfA[4], qfB[4];
    {
        const u16* qpA = Q + ((size_t)(b * 2048 + t0a + ml) * 2048 + h * 128);
        const u16* qpB = Q + ((size_t)(b * 2048 + t0b + ml) * 2048 + h * 128);
        #pragma unroll
        for (int kc = 0; kc < 4; ++kc) {
            qfA[kc] = *(const s16x8*)(qpA + kc * 32 + quad * 8);
            qfB[kc] = *(const s16x8*)(qpB + kc * 32 + quad * 8);
        }
    }

    s16x8 ones;
    #pragma unroll
    for (int j = 0; j < 8; ++j) ones[j] = (short)0x3F80; // bf16 1.0

    f32x4 OA[8] = {}, OB[8] = {};
    f32x4 LA = {}, LB = {};

    // Wave-level fragment bases (head-independent -> shared across the block's
    // 4 waves through L1). kf row = token, 8 consecutive d; vf row = d, 8
    // consecutive tokens. Both 16B-aligned.
    const u16* kfb = Kb + (size_t)(b * 2048 + ml) * 512 + kv * 128 + quad * 8;
    const u16* vfb = Vt + (size_t)(kv * 128 + ml) * 4096 + b * 2048 + quad * 8;

    for (int it = 0; it < nb; ++it) {
        const int s0 = it * 64;
        const bool actA = (it < na);

        // QK^T: kf direct from global; each kf feeds 2 MFMAs (A+B tiles)
        f32x4 Sa[4] = {}, Sb[4] = {};
        if (actA) {
            #pragma unroll
            for (int kc = 0; kc < 4; ++kc)
                #pragma unroll
                for (int ti = 0; ti < 4; ++ti) {
                    s16x8 kf = *(const s16x8*)(kfb + (size_t)(s0 + ti * 16) * 512 + kc * 32);
                    Sb[ti] = __builtin_amdgcn_mfma_f32_16x16x32_bf16(qfB[kc], kf, Sb[ti], 0, 0, 0);
                    Sa[ti] = __builtin_amdgcn_mfma_f32_16x16x32_bf16(qfA[kc], kf, Sa[ti], 0, 0, 0);
                }
        } else {
            #pragma unroll
            for (int kc = 0; kc < 4; ++kc)
                #pragma unroll
                for (int ti = 0; ti < 4; ++ti) {
                    s16x8 kf = *(const s16x8*)(kfb + (size_t)(s0 + ti * 16) * 512 + kc * 32);
                    Sb[ti] = __builtin_amdgcn_mfma_f32_16x16x32_bf16(qfB[kc], kf, Sb[ti], 0, 0, 0);
                }
        }

        // softmax (no max-shift): p = exp2(s); mask only on the tile's diagonal
        // iteration (provably the only one with masked elements)
        auto do_soft = [&](f32x4* S, int t0, int pslot, bool diag) {
            u16* pl = &Plds[wslot][pslot][0];
            #pragma unroll
            for (int r = 0; r < 4; ++r) {
                int qr = t0 + quad * 4 + r;
                int row = quad * 4 + r;
                #pragma unroll
                for (int ti = 0; ti < 4; ++ti) {
                    float e = fast_exp2(S[ti][r]);
                    if (diag && (s0 + ti * 16 + ml > qr)) e = 0.f;
                    union { float f; unsigned u; } cv; cv.f = e;
                    pl[row * 64 + (((ti * 2 + (ml >> 3)) ^ (row & 7)) * 8) + (ml & 7)] = (u16)(cv.u >> 16);
                }
            }
        };
        do_soft(Sb, t0b, 1, it == nb - 1);
        if (actA) do_soft(Sa, t0a, 0, it == na - 1);
        asm volatile("s_waitcnt lgkmcnt(0)" ::: "memory");
        s16x8 pfA[2], pfB[2];
        pfB[0] = *(const s16x8*)&Plds[wslot][1][ml * 64 + ((quad)     ^ m7) * 8];
        pfB[1] = *(const s16x8*)&Plds[wslot][1][ml * 64 + ((4 + quad) ^ m7) * 8];
        if (actA) {
            pfA[0] = *(const s16x8*)&Plds[wslot][0][ml * 64 + ((quad)     ^ m7) * 8];
            pfA[1] = *(const s16x8*)&Plds[wslot][0][ml * 64 + ((4 + quad) ^ m7) * 8];
        }
        asm volatile("s_waitcnt lgkmcnt(0)" ::: "memory");

        // PV + l: vf direct from global; each vf feeds 2 MFMAs (A+B tiles)
        if (actA) {
            #pragma unroll
            for (int c = 0; c < 2; ++c) {
                #pragma unroll
                for (int nt = 0; nt < 8; ++nt) {
                    s16x8 vf = *(const s16x8*)(vfb + (size_t)(nt * 16) * 4096 + s0 + c * 32);
                    OB[nt] = __builtin_amdgcn_mfma_f32_16x16x32_bf16(pfB[c], vf, OB[nt], 0, 0, 0);
                    OA[nt] = __builtin_amdgcn_mfma_f32_16x16x32_bf16(pfA[c], vf, OA[nt], 0, 0, 0);
                }
                LB = __builtin_amdgcn_mfma_f32_16x16x32_bf16(pfB[c], ones, LB, 0, 0, 0);
                LA = __builtin_amdgcn_mfma_f32_16x16x32_bf16(pfA[c], ones, LA, 0, 0, 0);
            }
        } else {
            #pragma unroll
            for (int c = 0; c < 2; ++c) {
                #pragma unroll
                for (int nt = 0; nt < 8; ++nt) {
                    s16x8 vf = *(const s16x8*)(vfb + (size_t)(nt * 16) * 4096 + s0 + c * 32);
                    OB[nt] = __builtin_amdgcn_mfma_f32_16x16x32_bf16(pfB[c], vf, OB[nt], 0, 0, 0);
                }
                LB = __builtin_amdgcn_mfma_f32_16x16x32_bf16(pfB[c], ones, LB, 0, 0, 0);
            }
        }
    }

    #pragma unroll
    for (int nt = 0; nt < 8; ++nt)
        #pragma unroll
        for (int r = 0; r < 4; ++r) {
            int col = h * 128 + nt * 16 + ml;
            O[(size_t)(b * 2048 + t0b + quad * 4 + r) * 2048 + col] = f2bf(OB[nt][r] / LB[r]);
            O[(size_t)(b * 2048 + t0a + quad * 4 + r) * 2048 + col] = f2bf(OA[nt][r] / LA[r]);
        }
}

extern "C" void kernel_launch(void* const* d_in, const int* in_sizes, int n_in,
                              void* d_out, int out_size, void* d_ws, size_t ws_size,
                              hipStream_t stream) {
    const float* x  = (const float*)d_in[0];
    const float* wq = (const float*)d_in[1];
    const float* wk = (const float*)d_in[2];
    const float* wv = (const float*)d_in[3];
    const float* wo = (const float*)d_in[4];
    float* out = (float*)d_out;
    char* ws = (char*)d_ws;

    const size_t MB = 1024 * 1024;
    // ws (52MB): [0,16M) xb (reused as ab) | [16M,32M) qb | [32M,36M) kb |
    //            [36M,40M) vtb | [40M,52M) wqkvb (reused as wob after qkv GEMM)
    u16* xb    = (u16*)(ws);
    u16* qb    = (u16*)(ws + 16 * MB);
    u16* kb    = (u16*)(ws + 32 * MB);
    u16* vtb   = (u16*)(ws + 36 * MB);
    u16* wqkvb = (u16*)(ws + 40 * MB);
    u16* ab    = xb;    // attn output over xb (x last read by qkv GEMM)
    u16* wob   = wqkvb; // wo bf16 over wqkvb (last read by qkv GEMM)

    cvt_all<<<7168, 256, 0, stream>>>(x, wq, wk, wv, xb, wqkvb);

    gemm128<4><<<dim3(24, 32), 256, 0, stream>>>(xb, wqkvb, qb, kb, vtb, 4096, 3072, 2048);

    cvt_kernel<<<2048, 256, 0, stream>>>(wo, wob, 524288); // wqkvb region now free

    // q pre-scaled by 1/sqrt(128)*log2(e)
    rope_kernel<<<20480, 256, 0, stream>>>(qb, kb, 4194304, 5242880, 0.12751743f);

    attn_kernel<<<512, 256, 0, stream>>>(qb, kb, vtb, ab);

    gemm128<1><<<dim3(16, 32), 256, 0, stream>>>(ab, wob, out, nullptr, nullptr, 4096, 2048, 2048);
}

// Round 5
// 409.706 us; speedup vs baseline: 1.0378x; 1.0378x over previous
//
#include <hip/hip_runtime.h>

typedef float f32x4 __attribute__((ext_vector_type(4)));
typedef short s16x8 __attribute__((ext_vector_type(8)));
typedef unsigned short u16;

__device__ __forceinline__ u16 f2bf(float f) {
    union { float f; unsigned u; } v; v.f = f;
    return (u16)((v.u + 0x7fffu + ((v.u >> 16) & 1u)) >> 16);
}
__device__ __forceinline__ float bf2f(u16 h) {
    union { unsigned u; float f; } v; v.u = ((unsigned)h) << 16;
    return v.f;
}
__device__ __forceinline__ float fast_exp2(float x) {
#if __has_builtin(__builtin_amdgcn_exp2f)
    return __builtin_amdgcn_exp2f(x);
#else
    return exp2f(x);
#endif
}

// async global->LDS, 16B/lane; LDS dest = wave-uniform base + lane*16 [m97/m104]
__device__ __forceinline__ void gload_lds16(const void* g, void* l) {
    __builtin_amdgcn_global_load_lds((__attribute__((address_space(1))) void*)g,
                                     (__attribute__((address_space(3))) void*)l, 16, 0, 0);
}

// Mega convert: x (1048576 units) -> xb, then wq|wk|wv (524288+131072+131072) -> wqkvb
// contiguous. 1 unit = 8 elems. Grid exactly 7168 blocks x 256.
__global__ __launch_bounds__(256) void cvt_all(const float* __restrict__ x,  const float* __restrict__ wq,
                                               const float* __restrict__ wk, const float* __restrict__ wv,
                                               u16* __restrict__ xb, u16* __restrict__ wqkvb) {
    int u = blockIdx.x * 256 + threadIdx.x;
    const float* src;
    u16* dst;
    if (u < 1048576) { src = x + (size_t)u * 8; dst = xb + (size_t)u * 8; }
    else {
        int w = u - 1048576;
        dst = wqkvb + (size_t)w * 8;
        if (w < 524288)      src = wq + (size_t)w * 8;
        else if (w < 655360) src = wk + (size_t)(w - 524288) * 8;
        else                 src = wv + (size_t)(w - 655360) * 8;
    }
    const float4* p = (const float4*)src;
    float4 a = p[0], b = p[1];
    s16x8 o;
    o[0] = f2bf(a.x); o[1] = f2bf(a.y); o[2] = f2bf(a.z); o[3] = f2bf(a.w);
    o[4] = f2bf(b.x); o[5] = f2bf(b.y); o[6] = f2bf(b.z); o[7] = f2bf(b.w);
    *(s16x8*)dst = o;
}

// fp32 -> bf16 elementwise (for wo after wqkv region is free)
__global__ __launch_bounds__(256) void cvt_kernel(const float* __restrict__ in,
                                                  u16* __restrict__ out, int n8) {
    int i = blockIdx.x * 256 + threadIdx.x;
    if (i >= n8) return;
    const float4* p = (const float4*)(in + (size_t)i * 8);
    float4 a = p[0], b = p[1];
    s16x8 o;
    o[0] = f2bf(a.x); o[1] = f2bf(a.y); o[2] = f2bf(a.z); o[3] = f2bf(a.w);
    o[4] = f2bf(b.x); o[5] = f2bf(b.y); o[6] = f2bf(b.z); o[7] = f2bf(b.w);
    *(s16x8*)(out + (size_t)i * 8) = o;
}

// C = A[M,K] @ B[N,K]^T, bf16 in. 128x128 tile, BK=64, global_load_lds staging,
// XOR-swizzled LDS. OUT=1: fp32 C[M,N]. OUT=4: fused qkv routing:
//   n<2048 -> bf16 Cq[m*2048+n]; 2048<=n<2560 -> bf16 Ck[m*512+(n-2048)];
//   n>=2560 -> bf16 transposed Cv[(n-2560)*M + m]
template<int OUT>
__global__ __launch_bounds__(256) void gemm128(const u16* __restrict__ A, const u16* __restrict__ B,
                                               void* __restrict__ C, void* __restrict__ Ck,
                                               void* __restrict__ Cv, int M, int N, int K) {
    __shared__ __align__(16) u16 Ald[128 * 64];
    __shared__ __align__(16) u16 Bld[128 * 64];
    const int t = threadIdx.x, wid = t >> 6, lane = t & 63;
    const int m0 = blockIdx.y * 128, n0 = blockIdx.x * 128;
    const int ml = lane & 15, quad = lane >> 4, m7 = ml & 7;
    const int wm = (wid & 1) * 64, wn = (wid >> 1) * 64;
    const int sr = lane >> 3, sc = lane & 7;

    f32x4 acc[4][4] = {};

    for (int k0 = 0; k0 < K; k0 += 64) {
        if (k0) __syncthreads();
        #pragma unroll
        for (int i = 0; i < 4; ++i) {
            int seg = wid * 4 + i;
            int r = seg * 8 + sr;
            int c = (sc ^ (r & 7)) * 8;
            gload_lds16(A + (size_t)(m0 + r) * K + k0 + c, &Ald[seg * 512]);
            gload_lds16(B + (size_t)(n0 + r) * K + k0 + c, &Bld[seg * 512]);
        }
        __syncthreads();
        #pragma unroll
        for (int kk = 0; kk < 64; kk += 32) {
            s16x8 af[4], bf[4];
            #pragma unroll
            for (int mi = 0; mi < 4; ++mi)
                af[mi] = *(const s16x8*)&Ald[(wm + mi * 16 + ml) * 64 + (((kk >> 3) + quad) ^ m7) * 8];
            #pragma unroll
            for (int ni = 0; ni < 4; ++ni)
                bf[ni] = *(const s16x8*)&Bld[(wn + ni * 16 + ml) * 64 + (((kk >> 3) + quad) ^ m7) * 8];
            #pragma unroll
            for (int mi = 0; mi < 4; ++mi)
                #pragma unroll
                for (int ni = 0; ni < 4; ++ni)
                    acc[mi][ni] = __builtin_amdgcn_mfma_f32_16x16x32_bf16(af[mi], bf[ni], acc[mi][ni], 0, 0, 0);
        }
    }
    // C/D layout: col=lane&15, row=quad*4+reg [m89/m91]
    #pragma unroll
    for (int mi = 0; mi < 4; ++mi)
        #pragma unroll
        for (int ni = 0; ni < 4; ++ni) {
            int gmb = m0 + wm + mi * 16 + quad * 4;
            int gn  = n0 + wn + ni * 16 + ml;
            if constexpr (OUT == 4) {
                if (n0 < 2048) {
                    #pragma unroll
                    for (int r = 0; r < 4; ++r)
                        ((u16*)C)[(size_t)(gmb + r) * 2048 + gn] = f2bf(acc[mi][ni][r]);
                } else if (n0 < 2560) {
                    #pragma unroll
                    for (int r = 0; r < 4; ++r)
                        ((u16*)Ck)[(size_t)(gmb + r) * 512 + (gn - 2048)] = f2bf(acc[mi][ni][r]);
                } else {
                    ushort4 v;
                    v.x = f2bf(acc[mi][ni][0]); v.y = f2bf(acc[mi][ni][1]);
                    v.z = f2bf(acc[mi][ni][2]); v.w = f2bf(acc[mi][ni][3]);
                    *(ushort4*)((u16*)Cv + (size_t)(gn - 2560) * M + gmb) = v;
                }
            } else {
                #pragma unroll
                for (int r = 0; r < 4; ++r)
                    ((float*)C)[(size_t)(gmb + r) * N + gn] = acc[mi][ni][r];
            }
        }
}

// Fused NeoX RoPE for q (16 heads, scaled) + k (4 heads). pos = tok % 2048.
// q pre-scaled by 1/sqrt(128)*log2(e) -> attention works in the log2 domain.
__global__ __launch_bounds__(256) void rope_kernel(u16* __restrict__ qb, u16* __restrict__ kb,
                                                   int nq, int ntot, float sq) {
    int idx = blockIdx.x * 256 + threadIdx.x;
    if (idx >= ntot) return;
    u16* base; int nheads; float scl; int id;
    if (idx < nq) { base = qb; nheads = 16; scl = sq;  id = idx; }
    else          { base = kb; nheads = 4;  scl = 1.f; id = idx - nq; }
    int i = id & 63;
    int rest = id >> 6;
    int hh = rest % nheads;
    int tok = rest / nheads;
    int tpos = tok & 2047;
    u16* row = base + (size_t)tok * nheads * 128 + hh * 128;
    float x1 = bf2f(row[i]);
    float x2 = bf2f(row[i + 64]);
    float inv = expf(-(float)i * 0.14391156731570787f); // 10000^(-i/64)
    float ang = (float)tpos * inv;
    float s, c;
    sincosf(ang, &s, &c);
    row[i]      = f2bf((x1 * c - x2 * s) * scl);
    row[i + 64] = f2bf((x2 * c + x1 * s) * scl);
}

// Flash attention v5 = v3 + T14 register-prefetch staging.
// v3 (109.6us): one q-tile/block, 4 blocks/CU (40KB LDS), balanced q-tile
// permutation. v4 taught: operand reads MUST come from LDS (global-direct
// regressed 2x). v5 removes v3's remaining exposed staging drain: prefetch
// tile it+1 into 32 VGPRs (global loads issued right after this tile's LDS
// writes), ds_write them at the start of the NEXT iteration. The global
// latency hides under a full compute phase (QK+softmax+PV ~1000+cyc) instead
// of being serially drained at a vmcnt(0) barrier each iteration. LDS stays
// 40KB -> 4 blocks/CU; bytes/layout identical to the gload_lds path (same
// swizzled global source, same linear seg*512+lane*16 dest).
__global__ __launch_bounds__(256, 4) void attn_kernel(const u16* __restrict__ Q, const u16* __restrict__ Kb,
                                                      const u16* __restrict__ Vt, u16* __restrict__ O) {
    __shared__ __align__(16) u16 Klds[64 * 128];   // 16KB
    __shared__ __align__(16) u16 Vlds[128 * 64];   // 16KB
    __shared__ __align__(16) u16 Plds[4][16 * 64]; // 8KB
    const int t = threadIdx.x, wslot = t >> 6, lane = t & 63;
    const int kv = blockIdx.y, b = blockIdx.z;
    const int g = kv + 4 * b;            // 0..7
    const int bx = blockIdx.x;           // 0..127
    int qt;                              // bijective per (kv,b); balances CU loads
    switch ((g >> 1) & 3) {
        case 0:  qt = bx; break;
        case 1:  qt = 127 - bx; break;
        case 2:  qt = (bx + 64) & 127; break;
        default: qt = (63 - bx) & 127; break;
    }
    const int h = kv * 4 + wslot;
    const int ml = lane & 15, quad = lane >> 4, m7 = ml & 7;
    const int t0 = qt * 16;
    const int n = (qt >> 2) + 1;

    // Q fragments: A layout m=lane&15, k=quad*8+j [m120]
    s16x8 qf[4];
    {
        const u16* qp = Q + ((size_t)(b * 2048 + t0 + ml) * 2048 + h * 128);
        #pragma unroll
        for (int kc = 0; kc < 4; ++kc)
            qf[kc] = *(const s16x8*)(qp + kc * 32 + quad * 8);
    }

    s16x8 ones;
    #pragma unroll
    for (int j = 0; j < 8; ++j) ones[j] = (short)0x3F80; // bf16 1.0

    f32x4 Oa[8] = {};
    f32x4 L = {};

    // Per-wave prefetch state: 4 K segments + 4 V segments (32 VGPRs).
    // Global source carries the XOR swizzle (m173); LDS dest is linear.
    s16x8 kpf[4], vpf[4];
    // per-seg invariant address parts
    const int seg0 = wslot * 4;
    auto issue = [&](int it) {
        const int s0 = it * 64;
        #pragma unroll
        for (int i = 0; i < 4; ++i) {
            int seg = seg0 + i;
            int kr = seg * 4 + (lane >> 4);
            int kc = ((lane & 15) ^ (kr & 7)) * 8;
            kpf[i] = *(const s16x8*)(Kb + (size_t)(b * 2048 + s0 + kr) * 512 + kv * 128 + kc);
            int vr = seg * 8 + (lane >> 3);
            int vc = ((lane & 7) ^ (vr & 7)) * 8;
            vpf[i] = *(const s16x8*)(Vt + (size_t)(kv * 128 + vr) * 4096 + b * 2048 + s0 + vc);
        }
    };

    issue(0);

    for (int it = 0; it < n; ++it) {
        if (it) __syncthreads(); // all waves done reading previous K/V tile
        // commit prefetched tile to LDS (linear dest: seg*512 + lane*8 u16)
        #pragma unroll
        for (int i = 0; i < 4; ++i) {
            int seg = seg0 + i;
            *(s16x8*)&Klds[seg * 512 + lane * 8] = kpf[i];
            *(s16x8*)&Vlds[seg * 512 + lane * 8] = vpf[i];
        }
        if (it + 1 < n) issue(it + 1); // overwrites kpf/vpf AFTER the ds_writes (WAR)
        __syncthreads(); // writes visible to all waves

        const int s0 = it * 64;

        // QK^T
        f32x4 S[4] = {};
        #pragma unroll
        for (int kc = 0; kc < 4; ++kc)
            #pragma unroll
            for (int ti = 0; ti < 4; ++ti) {
                s16x8 kf = *(const s16x8*)&Klds[(ti * 16 + ml) * 128 + ((kc * 4 + quad) ^ m7) * 8];
                S[ti] = __builtin_amdgcn_mfma_f32_16x16x32_bf16(qf[kc], kf, S[ti], 0, 0, 0);
            }

        // softmax (no max-shift): p = exp2(s); causal mask only on diagonal tile
        {
            u16* pl = &Plds[wslot][0];
            const bool diag = (it == n - 1);
            #pragma unroll
            for (int r = 0; r < 4; ++r) {
                int qr = t0 + quad * 4 + r;
                int row = quad * 4 + r;
                #pragma unroll
                for (int ti = 0; ti < 4; ++ti) {
                    float e = fast_exp2(S[ti][r]);
                    if (diag && (s0 + ti * 16 + ml > qr)) e = 0.f;
                    union { float f; unsigned u; } cv; cv.f = e;
                    pl[row * 64 + (((ti * 2 + (ml >> 3)) ^ (row & 7)) * 8) + (ml & 7)] = (u16)(cv.u >> 16);
                }
            }
        }
        asm volatile("s_waitcnt lgkmcnt(0)" ::: "memory");
        s16x8 pf[2];
        pf[0] = *(const s16x8*)&Plds[wslot][ml * 64 + ((quad)     ^ m7) * 8];
        pf[1] = *(const s16x8*)&Plds[wslot][ml * 64 + ((4 + quad) ^ m7) * 8];
        asm volatile("s_waitcnt lgkmcnt(0)" ::: "memory");

        // PV + l
        #pragma unroll
        for (int c = 0; c < 2; ++c) {
            #pragma unroll
            for (int nt = 0; nt < 8; ++nt) {
                s16x8 vf = *(const s16x8*)&Vlds[(nt * 16 + ml) * 64 + ((c * 4 + quad) ^ m7) * 8];
                Oa[nt] = __builtin_amdgcn_mfma_f32_16x16x32_bf16(pf[c], vf, Oa[nt], 0, 0, 0);
            }
            L = __builtin_amdgcn_mfma_f32_16x16x32_bf16(pf[c], ones, L, 0, 0, 0);
        }
    }

    #pragma unroll
    for (int nt = 0; nt < 8; ++nt)
        #pragma unroll
        for (int r = 0; r < 4; ++r) {
            int col = h * 128 + nt * 16 + ml;
            O[(size_t)(b * 2048 + t0 + quad * 4 + r) * 2048 + col] = f2bf(Oa[nt][r] / L[r]);
        }
}

extern "C" void kernel_launch(void* const* d_in, const int* in_sizes, int n_in,
                              void* d_out, int out_size, void* d_ws, size_t ws_size,
                              hipStream_t stream) {
    const float* x  = (const float*)d_in[0];
    const float* wq = (const float*)d_in[1];
    const float* wk = (const float*)d_in[2];
    const float* wv = (const float*)d_in[3];
    const float* wo = (const float*)d_in[4];
    float* out = (float*)d_out;
    char* ws = (char*)d_ws;

    const size_t MB = 1024 * 1024;
    // ws (52MB): [0,16M) xb (reused as ab) | [16M,32M) qb | [32M,36M) kb |
    //            [36M,40M) vtb | [40M,52M) wqkvb (reused as wob after qkv GEMM)
    u16* xb    = (u16*)(ws);
    u16* qb    = (u16*)(ws + 16 * MB);
    u16* kb    = (u16*)(ws + 32 * MB);
    u16* vtb   = (u16*)(ws + 36 * MB);
    u16* wqkvb = (u16*)(ws + 40 * MB);
    u16* ab    = xb;    // attn output over xb (x last read by qkv GEMM)
    u16* wob   = wqkvb; // wo bf16 over wqkvb (last read by qkv GEMM)

    cvt_all<<<7168, 256, 0, stream>>>(x, wq, wk, wv, xb, wqkvb);

    gemm128<4><<<dim3(24, 32), 256, 0, stream>>>(xb, wqkvb, qb, kb, vtb, 4096, 3072, 2048);

    cvt_kernel<<<2048, 256, 0, stream>>>(wo, wob, 524288); // wqkvb region now free

    // q pre-scaled by 1/sqrt(128)*log2(e)
    rope_kernel<<<20480, 256, 0, stream>>>(qb, kb, 4194304, 5242880, 0.12751743f);

    attn_kernel<<<dim3(128, 4, 2), 256, 0, stream>>>(qb, kb, vtb, ab);

    gemm128<1><<<dim3(16, 32), 256, 0, stream>>>(ab, wob, out, nullptr, nullptr, 4096, 2048, 2048);
}

// Round 6
// 342.275 us; speedup vs baseline: 1.2423x; 1.1970x over previous
//
#include <hip/hip_runtime.h>

typedef float f32x4 __attribute__((ext_vector_type(4)));
typedef short s16x8 __attribute__((ext_vector_type(8)));
typedef unsigned short u16;

__device__ __forceinline__ u16 f2bf(float f) {
    union { float f; unsigned u; } v; v.f = f;
    return (u16)((v.u + 0x7fffu + ((v.u >> 16) & 1u)) >> 16);
}
__device__ __forceinline__ float bf2f(u16 h) {
    union { unsigned u; float f; } v; v.u = ((unsigned)h) << 16;
    return v.f;
}
__device__ __forceinline__ float fast_exp2(float x) {
#if __has_builtin(__builtin_amdgcn_exp2f)
    return __builtin_amdgcn_exp2f(x);
#else
    return exp2f(x);
#endif
}

// async global->LDS, 16B/lane; LDS dest = wave-uniform base + lane*16 [m97/m104]
__device__ __forceinline__ void gload_lds16(const void* g, void* l) {
    __builtin_amdgcn_global_load_lds((__attribute__((address_space(1))) void*)g,
                                     (__attribute__((address_space(3))) void*)l, 16, 0, 0);
}

// Mega convert: x (1048576 units) -> xb, then wq|wk|wv (524288+131072+131072) -> wqkvb
// contiguous. 1 unit = 8 elems. Grid exactly 7168 blocks x 256.
__global__ __launch_bounds__(256) void cvt_all(const float* __restrict__ x,  const float* __restrict__ wq,
                                               const float* __restrict__ wk, const float* __restrict__ wv,
                                               u16* __restrict__ xb, u16* __restrict__ wqkvb) {
    int u = blockIdx.x * 256 + threadIdx.x;
    const float* src;
    u16* dst;
    if (u < 1048576) { src = x + (size_t)u * 8; dst = xb + (size_t)u * 8; }
    else {
        int w = u - 1048576;
        dst = wqkvb + (size_t)w * 8;
        if (w < 524288)      src = wq + (size_t)w * 8;
        else if (w < 655360) src = wk + (size_t)(w - 524288) * 8;
        else                 src = wv + (size_t)(w - 655360) * 8;
    }
    const float4* p = (const float4*)src;
    float4 a = p[0], b = p[1];
    s16x8 o;
    o[0] = f2bf(a.x); o[1] = f2bf(a.y); o[2] = f2bf(a.z); o[3] = f2bf(a.w);
    o[4] = f2bf(b.x); o[5] = f2bf(b.y); o[6] = f2bf(b.z); o[7] = f2bf(b.w);
    *(s16x8*)dst = o;
}

// fp32 -> bf16 elementwise (for wo after wqkv region is free)
__global__ __launch_bounds__(256) void cvt_kernel(const float* __restrict__ in,
                                                  u16* __restrict__ out, int n8) {
    int i = blockIdx.x * 256 + threadIdx.x;
    if (i >= n8) return;
    const float4* p = (const float4*)(in + (size_t)i * 8);
    float4 a = p[0], b = p[1];
    s16x8 o;
    o[0] = f2bf(a.x); o[1] = f2bf(a.y); o[2] = f2bf(a.z); o[3] = f2bf(a.w);
    o[4] = f2bf(b.x); o[5] = f2bf(b.y); o[6] = f2bf(b.z); o[7] = f2bf(b.w);
    *(s16x8*)(out + (size_t)i * 8) = o;
}

// zero Oacc+Lacc (contiguous). n4 float4 units.
__global__ __launch_bounds__(256) void zero_acc(float* __restrict__ p, int n4) {
    int i = blockIdx.x * 256 + threadIdx.x;
    if (i >= n4) return;
    float4 z = {0.f, 0.f, 0.f, 0.f};
    ((float4*)p)[i] = z;
}

// normalize split-region rows: ab[b][1024+tokp][col] = Oacc[b][tokp][col] / Lacc[row][head]
__global__ __launch_bounds__(256) void norm_split(const float* __restrict__ Oacc,
                                                  const float* __restrict__ Lacc,
                                                  u16* __restrict__ ab) {
    int i = blockIdx.x * 256 + threadIdx.x;     // 0..524287
    int rowi = i >> 8;                          // 0..2047 (= b*1024 + tokp)
    int col0 = (i & 255) * 8;                   // 8 cols, within one head (8|128)
    const float* po = Oacc + ((size_t)rowi << 11) + col0;
    float Lv = Lacc[rowi * 16 + (col0 >> 7)];
    float inv = 1.0f / Lv;
    int b = rowi >> 10, tokp = rowi & 1023;
    u16* pd = ab + ((size_t)(b * 2048 + 1024 + tokp) << 11) + col0;
    float4 a = ((const float4*)po)[0], c = ((const float4*)po)[1];
    s16x8 o;
    o[0] = f2bf(a.x * inv); o[1] = f2bf(a.y * inv); o[2] = f2bf(a.z * inv); o[3] = f2bf(a.w * inv);
    o[4] = f2bf(c.x * inv); o[5] = f2bf(c.y * inv); o[6] = f2bf(c.z * inv); o[7] = f2bf(c.w * inv);
    *(s16x8*)pd = o;
}

// C = A[M,K] @ B[N,K]^T, bf16 in. 128x128 tile, BK=64, global_load_lds staging,
// XOR-swizzled LDS. OUT=1: fp32 C[M,N]. OUT=4: fused qkv routing:
//   n<2048 -> bf16 Cq[m*2048+n]; 2048<=n<2560 -> bf16 Ck[m*512+(n-2048)];
//   n>=2560 -> bf16 transposed Cv[(n-2560)*M + m]
template<int OUT>
__global__ __launch_bounds__(256) void gemm128(const u16* __restrict__ A, const u16* __restrict__ B,
                                               void* __restrict__ C, void* __restrict__ Ck,
                                               void* __restrict__ Cv, int M, int N, int K) {
    __shared__ __align__(16) u16 Ald[128 * 64];
    __shared__ __align__(16) u16 Bld[128 * 64];
    const int t = threadIdx.x, wid = t >> 6, lane = t & 63;
    const int m0 = blockIdx.y * 128, n0 = blockIdx.x * 128;
    const int ml = lane & 15, quad = lane >> 4, m7 = ml & 7;
    const int wm = (wid & 1) * 64, wn = (wid >> 1) * 64;
    const int sr = lane >> 3, sc = lane & 7;

    f32x4 acc[4][4] = {};

    for (int k0 = 0; k0 < K; k0 += 64) {
        if (k0) __syncthreads();
        #pragma unroll
        for (int i = 0; i < 4; ++i) {
            int seg = wid * 4 + i;
            int r = seg * 8 + sr;
            int c = (sc ^ (r & 7)) * 8;
            gload_lds16(A + (size_t)(m0 + r) * K + k0 + c, &Ald[seg * 512]);
            gload_lds16(B + (size_t)(n0 + r) * K + k0 + c, &Bld[seg * 512]);
        }
        __syncthreads();
        #pragma unroll
        for (int kk = 0; kk < 64; kk += 32) {
            s16x8 af[4], bf[4];
            #pragma unroll
            for (int mi = 0; mi < 4; ++mi)
                af[mi] = *(const s16x8*)&Ald[(wm + mi * 16 + ml) * 64 + (((kk >> 3) + quad) ^ m7) * 8];
            #pragma unroll
            for (int ni = 0; ni < 4; ++ni)
                bf[ni] = *(const s16x8*)&Bld[(wn + ni * 16 + ml) * 64 + (((kk >> 3) + quad) ^ m7) * 8];
            #pragma unroll
            for (int mi = 0; mi < 4; ++mi)
                #pragma unroll
                for (int ni = 0; ni < 4; ++ni)
                    acc[mi][ni] = __builtin_amdgcn_mfma_f32_16x16x32_bf16(af[mi], bf[ni], acc[mi][ni], 0, 0, 0);
        }
    }
    // C/D layout: col=lane&15, row=quad*4+reg [m89/m91]
    #pragma unroll
    for (int mi = 0; mi < 4; ++mi)
        #pragma unroll
        for (int ni = 0; ni < 4; ++ni) {
            int gmb = m0 + wm + mi * 16 + quad * 4;
            int gn  = n0 + wn + ni * 16 + ml;
            if constexpr (OUT == 4) {
                if (n0 < 2048) {
                    #pragma unroll
                    for (int r = 0; r < 4; ++r)
                        ((u16*)C)[(size_t)(gmb + r) * 2048 + gn] = f2bf(acc[mi][ni][r]);
                } else if (n0 < 2560) {
                    #pragma unroll
                    for (int r = 0; r < 4; ++r)
                        ((u16*)Ck)[(size_t)(gmb + r) * 512 + (gn - 2048)] = f2bf(acc[mi][ni][r]);
                } else {
                    ushort4 v;
                    v.x = f2bf(acc[mi][ni][0]); v.y = f2bf(acc[mi][ni][1]);
                    v.z = f2bf(acc[mi][ni][2]); v.w = f2bf(acc[mi][ni][3]);
                    *(ushort4*)((u16*)Cv + (size_t)(gn - 2560) * M + gmb) = v;
                }
            } else {
                #pragma unroll
                for (int r = 0; r < 4; ++r)
                    ((float*)C)[(size_t)(gmb + r) * N + gn] = acc[mi][ni][r];
            }
        }
}

// Fused NeoX RoPE for q (16 heads, scaled) + k (4 heads). pos = tok % 2048.
// q pre-scaled by 1/sqrt(128)*log2(e) -> attention works in the log2 domain.
__global__ __launch_bounds__(256) void rope_kernel(u16* __restrict__ qb, u16* __restrict__ kb,
                                                   int nq, int ntot, float sq) {
    int idx = blockIdx.x * 256 + threadIdx.x;
    if (idx >= ntot) return;
    u16* base; int nheads; float scl; int id;
    if (idx < nq) { base = qb; nheads = 16; scl = sq;  id = idx; }
    else          { base = kb; nheads = 4;  scl = 1.f; id = idx - nq; }
    int i = id & 63;
    int rest = id >> 6;
    int hh = rest % nheads;
    int tok = rest / nheads;
    int tpos = tok & 2047;
    u16* row = base + (size_t)tok * nheads * 128 + hh * 128;
    float x1 = bf2f(row[i]);
    float x2 = bf2f(row[i + 64]);
    float inv = expf(-(float)i * 0.14391156731570787f); // 10000^(-i/64)
    float ang = (float)tpos * inv;
    float s, c;
    sincosf(ang, &s, &c);
    row[i]      = f2bf((x1 * c - x2 * s) * scl);
    row[i + 64] = f2bf((x2 * c + x1 * s) * scl);
}

// ---------- v3 attention (fallback when workspace too small) ----------
__global__ __launch_bounds__(256, 4) void attn_kernel(const u16* __restrict__ Q, const u16* __restrict__ Kb,
                                                      const u16* __restrict__ Vt, u16* __restrict__ O) {
    __shared__ __align__(16) u16 Klds[64 * 128];   // 16KB
    __shared__ __align__(16) u16 Vlds[128 * 64];   // 16KB
    __shared__ __align__(16) u16 Plds[4][16 * 64]; // 8KB
    const int t = threadIdx.x, wslot = t >> 6, lane = t & 63;
    const int kv = blockIdx.y, b = blockIdx.z;
    const int g = kv + 4 * b;
    const int bx = blockIdx.x;
    int qt;
    switch ((g >> 1) & 3) {
        case 0:  qt = bx; break;
        case 1:  qt = 127 - bx; break;
        case 2:  qt = (bx + 64) & 127; break;
        default: qt = (63 - bx) & 127; break;
    }
    const int h = kv * 4 + wslot;
    const int ml = lane & 15, quad = lane >> 4, m7 = ml & 7;
    const int t0 = qt * 16;
    const int n = (qt >> 2) + 1;

    s16x8 qf[4];
    {
        const u16* qp = Q + ((size_t)(b * 2048 + t0 + ml) * 2048 + h * 128);
        #pragma unroll
        for (int kc = 0; kc < 4; ++kc)
            qf[kc] = *(const s16x8*)(qp + kc * 32 + quad * 8);
    }

    s16x8 ones;
    #pragma unroll
    for (int j = 0; j < 8; ++j) ones[j] = (short)0x3F80;

    f32x4 Oa[8] = {};
    f32x4 L = {};

    for (int it = 0; it < n; ++it) {
        const int s0 = it * 64;
        if (it) __syncthreads();
        #pragma unroll
        for (int i = 0; i < 4; ++i) {
            int seg = wslot * 4 + i;
            int kr = seg * 4 + (lane >> 4);
            int kc = ((lane & 15) ^ (kr & 7)) * 8;
            gload_lds16(Kb + (size_t)(b * 2048 + s0 + kr) * 512 + kv * 128 + kc, &Klds[seg * 512]);
            int vr = seg * 8 + (lane >> 3);
            int vc = ((lane & 7) ^ (vr & 7)) * 8;
            gload_lds16(Vt + (size_t)(kv * 128 + vr) * 4096 + b * 2048 + s0 + vc, &Vlds[seg * 512]);
        }
        __syncthreads();

        f32x4 S[4] = {};
        #pragma unroll
        for (int kc = 0; kc < 4; ++kc)
            #pragma unroll
            for (int ti = 0; ti < 4; ++ti) {
                s16x8 kf = *(const s16x8*)&Klds[(ti * 16 + ml) * 128 + ((kc * 4 + quad) ^ m7) * 8];
                S[ti] = __builtin_amdgcn_mfma_f32_16x16x32_bf16(qf[kc], kf, S[ti], 0, 0, 0);
            }

        {
            u16* pl = &Plds[wslot][0];
            const bool diag = (it == n - 1);
            #pragma unroll
            for (int r = 0; r < 4; ++r) {
                int qr = t0 + quad * 4 + r;
                int row = quad * 4 + r;
                #pragma unroll
                for (int ti = 0; ti < 4; ++ti) {
                    float e = fast_exp2(S[ti][r]);
                    if (diag && (s0 + ti * 16 + ml > qr)) e = 0.f;
                    union { float f; unsigned u; } cv; cv.f = e;
                    pl[row * 64 + (((ti * 2 + (ml >> 3)) ^ (row & 7)) * 8) + (ml & 7)] = (u16)(cv.u >> 16);
                }
            }
        }
        asm volatile("s_waitcnt lgkmcnt(0)" ::: "memory");
        s16x8 pf[2];
        pf[0] = *(const s16x8*)&Plds[wslot][ml * 64 + ((quad)     ^ m7) * 8];
        pf[1] = *(const s16x8*)&Plds[wslot][ml * 64 + ((4 + quad) ^ m7) * 8];
        asm volatile("s_waitcnt lgkmcnt(0)" ::: "memory");

        #pragma unroll
        for (int c = 0; c < 2; ++c) {
            #pragma unroll
            for (int nt = 0; nt < 8; ++nt) {
                s16x8 vf = *(const s16x8*)&Vlds[(nt * 16 + ml) * 64 + ((c * 4 + quad) ^ m7) * 8];
                Oa[nt] = __builtin_amdgcn_mfma_f32_16x16x32_bf16(pf[c], vf, Oa[nt], 0, 0, 0);
            }
            L = __builtin_amdgcn_mfma_f32_16x16x32_bf16(pf[c], ones, L, 0, 0, 0);
        }
    }

    #pragma unroll
    for (int nt = 0; nt < 8; ++nt)
        #pragma unroll
        for (int r = 0; r < 4; ++r) {
            int col = h * 128 + nt * 16 + ml;
            O[(size_t)(b * 2048 + t0 + quad * 4 + r) * 2048 + col] = f2bf(Oa[nt][r] / L[r]);
        }
}

// ---------- v6 attention: split-KV for load balance ----------
// Evidence: v3's OccupancyPercent 25.2% == sum/max (66/32) of co-resident block
// lengths -> wall set by the 32-iter block running alone. Lengths 17..32 can't
// be equalized by grouping; but this softmax is max-free (log2 domain, no
// rescale), so partial (O,l) over disjoint KV ranges are ADDITIVE. Split every
// qt>=64 into two halves (lengths 8..16); halves atomicAdd f32 partials into
// Oacc/Lacc (zeroed), norm_split divides. All lengths <=16, 1536 blocks
// launched longest-first; id&7 pins each (kv,b) group to one XCD (1MB K/V set
// in its 4MB L2). LDS 40KB, 4 blocks/CU; occupancy sustained by dynamic refill.
__global__ __launch_bounds__(256, 4) void attn_split(const u16* __restrict__ Q, const u16* __restrict__ Kb,
                                                     const u16* __restrict__ Vt, u16* __restrict__ O,
                                                     float* __restrict__ Oacc, float* __restrict__ Lacc) {
    __shared__ __align__(16) u16 Klds[64 * 128];   // 16KB
    __shared__ __align__(16) u16 Vlds[128 * 64];   // 16KB
    __shared__ __align__(16) u16 Plds[4][16 * 64]; // 8KB
    const int t = threadIdx.x, wslot = t >> 6, lane = t & 63;
    const int id = blockIdx.x;          // 1536 blocks
    const int g = id & 7, w = id >> 3;  // g: XCD-pinned group; w: work unit (length-descending)
    const int kv = g & 3, b = g >> 2;

    int qt, it0, it1, nfull;
    bool partial;
    if (w < 128) {                       // split halves, qt 127..64 (len 16..8)
        qt = 127 - (w >> 1);
        nfull = (qt >> 2) + 1;           // 32..17
        int nA = nfull >> 1;
        if ((w & 1) == 0) { it0 = 0;  it1 = nA; }
        else              { it0 = nA; it1 = nfull; }
        partial = true;
    } else {                             // unsplit, qt 63..0 (len 16..1)
        qt = 191 - w;
        nfull = (qt >> 2) + 1;
        it0 = 0; it1 = nfull;
        partial = false;
    }

    const int h = kv * 4 + wslot;
    const int ml = lane & 15, quad = lane >> 4, m7 = ml & 7;
    const int t0 = qt * 16;

    // Q fragments: A layout m=lane&15, k=quad*8+j [m120]
    s16x8 qf[4];
    {
        const u16* qp = Q + ((size_t)(b * 2048 + t0 + ml) * 2048 + h * 128);
        #pragma unroll
        for (int kc = 0; kc < 4; ++kc)
            qf[kc] = *(const s16x8*)(qp + kc * 32 + quad * 8);
    }

    s16x8 ones;
    #pragma unroll
    for (int j = 0; j < 8; ++j) ones[j] = (short)0x3F80; // bf16 1.0

    f32x4 Oa[8] = {};
    f32x4 L = {};

    for (int it = it0; it < it1; ++it) {
        const int s0 = it * 64;
        if (it != it0) __syncthreads(); // all waves done reading previous K/V tile
        #pragma unroll
        for (int i = 0; i < 4; ++i) {
            int seg = wslot * 4 + i;
            int kr = seg * 4 + (lane >> 4);
            int kc = ((lane & 15) ^ (kr & 7)) * 8;
            gload_lds16(Kb + (size_t)(b * 2048 + s0 + kr) * 512 + kv * 128 + kc, &Klds[seg * 512]);
            int vr = seg * 8 + (lane >> 3);
            int vc = ((lane & 7) ^ (vr & 7)) * 8;
            gload_lds16(Vt + (size_t)(kv * 128 + vr) * 4096 + b * 2048 + s0 + vc, &Vlds[seg * 512]);
        }
        __syncthreads(); // staging drained (vmcnt0)

        // QK^T
        f32x4 S[4] = {};
        #pragma unroll
        for (int kc = 0; kc < 4; ++kc)
            #pragma unroll
            for (int ti = 0; ti < 4; ++ti) {
                s16x8 kf = *(const s16x8*)&Klds[(ti * 16 + ml) * 128 + ((kc * 4 + quad) ^ m7) * 8];
                S[ti] = __builtin_amdgcn_mfma_f32_16x16x32_bf16(qf[kc], kf, S[ti], 0, 0, 0);
            }

        // softmax (no max-shift): p = exp2(s); causal mask only on diagonal tile
        {
            u16* pl = &Plds[wslot][0];
            const bool diag = (it == nfull - 1);
            #pragma unroll
            for (int r = 0; r < 4; ++r) {
                int qr = t0 + quad * 4 + r;
                int row = quad * 4 + r;
                #pragma unroll
                for (int ti = 0; ti < 4; ++ti) {
                    float e = fast_exp2(S[ti][r]);
                    if (diag && (s0 + ti * 16 + ml > qr)) e = 0.f;
                    union { float f; unsigned u; } cv; cv.f = e;
                    pl[row * 64 + (((ti * 2 + (ml >> 3)) ^ (row & 7)) * 8) + (ml & 7)] = (u16)(cv.u >> 16);
                }
            }
        }
        asm volatile("s_waitcnt lgkmcnt(0)" ::: "memory");
        s16x8 pf[2];
        pf[0] = *(const s16x8*)&Plds[wslot][ml * 64 + ((quad)     ^ m7) * 8];
        pf[1] = *(const s16x8*)&Plds[wslot][ml * 64 + ((4 + quad) ^ m7) * 8];
        asm volatile("s_waitcnt lgkmcnt(0)" ::: "memory");

        // PV + l
        #pragma unroll
        for (int c = 0; c < 2; ++c) {
            #pragma unroll
            for (int nt = 0; nt < 8; ++nt) {
                s16x8 vf = *(const s16x8*)&Vlds[(nt * 16 + ml) * 64 + ((c * 4 + quad) ^ m7) * 8];
                Oa[nt] = __builtin_amdgcn_mfma_f32_16x16x32_bf16(pf[c], vf, Oa[nt], 0, 0, 0);
            }
            L = __builtin_amdgcn_mfma_f32_16x16x32_bf16(pf[c], ones, L, 0, 0, 0);
        }
    }

    if (!partial) {
        #pragma unroll
        for (int nt = 0; nt < 8; ++nt)
            #pragma unroll
            for (int r = 0; r < 4; ++r) {
                int col = h * 128 + nt * 16 + ml;
                O[(size_t)(b * 2048 + t0 + quad * 4 + r) * 2048 + col] = f2bf(Oa[nt][r] / L[r]);
            }
    } else {
        // additive partials: Oacc[b][tokp][2048], Lacc[row][16]
        const int tokp = (qt - 64) * 16;
        #pragma unroll
        for (int nt = 0; nt < 8; ++nt)
            #pragma unroll
            for (int r = 0; r < 4; ++r) {
                size_t row = (size_t)(b * 1024 + tokp + quad * 4 + r);
                atomicAdd(&Oacc[row * 2048 + h * 128 + nt * 16 + ml], Oa[nt][r]);
            }
        if (ml == 0) {
            #pragma unroll
            for (int r = 0; r < 4; ++r) {
                size_t row = (size_t)(b * 1024 + tokp + quad * 4 + r);
                atomicAdd(&Lacc[row * 16 + h], L[r]);
            }
        }
    }
}

extern "C" void kernel_launch(void* const* d_in, const int* in_sizes, int n_in,
                              void* d_out, int out_size, void* d_ws, size_t ws_size,
                              hipStream_t stream) {
    const float* x  = (const float*)d_in[0];
    const float* wq = (const float*)d_in[1];
    const float* wk = (const float*)d_in[2];
    const float* wv = (const float*)d_in[3];
    const float* wo = (const float*)d_in[4];
    float* out = (float*)d_out;
    char* ws = (char*)d_ws;

    const size_t MB = 1024 * 1024;
    // ws (52MB + optional 17MB): [0,16M) xb (reused as ab) | [16M,32M) qb |
    // [32M,36M) kb | [36M,40M) vtb | [40M,52M) wqkvb (reused as wob) |
    // [52M,68M) Oacc f32 | [68M,68.125M) Lacc f32   (split path only)
    u16* xb    = (u16*)(ws);
    u16* qb    = (u16*)(ws + 16 * MB);
    u16* kb    = (u16*)(ws + 32 * MB);
    u16* vtb   = (u16*)(ws + 36 * MB);
    u16* wqkvb = (u16*)(ws + 40 * MB);
    u16* ab    = xb;    // attn output over xb (x last read by qkv GEMM)
    u16* wob   = wqkvb; // wo bf16 over wqkvb (last read by qkv GEMM)

    const bool split = ws_size >= 70 * MB;

    cvt_all<<<7168, 256, 0, stream>>>(x, wq, wk, wv, xb, wqkvb);

    gemm128<4><<<dim3(24, 32), 256, 0, stream>>>(xb, wqkvb, qb, kb, vtb, 4096, 3072, 2048);

    cvt_kernel<<<2048, 256, 0, stream>>>(wo, wob, 524288); // wqkvb region now free

    // q pre-scaled by 1/sqrt(128)*log2(e)
    rope_kernel<<<20480, 256, 0, stream>>>(qb, kb, 4194304, 5242880, 0.12751743f);

    if (split) {
        float* Oacc = (float*)(ws + 52 * MB);
        float* Lacc = (float*)(ws + 68 * MB);
        // zero Oacc (16MB) + Lacc (128KB) in one pass: 4227072 floats = 1056768 float4
        zero_acc<<<4128, 256, 0, stream>>>(Oacc, 1056768);
        attn_split<<<1536, 256, 0, stream>>>(qb, kb, vtb, ab, Oacc, Lacc);
        norm_split<<<2048, 256, 0, stream>>>(Oacc, Lacc, ab);
    } else {
        attn_kernel<<<dim3(128, 4, 2), 256, 0, stream>>>(qb, kb, vtb, ab);
    }

    gemm128<1><<<dim3(16, 32), 256, 0, stream>>>(ab, wob, out, nullptr, nullptr, 4096, 2048, 2048);
}

// Round 8
// 323.848 us; speedup vs baseline: 1.3130x; 1.0569x over previous
//
#include <hip/hip_runtime.h>

typedef float f32x4 __attribute__((ext_vector_type(4)));
typedef short s16x8 __attribute__((ext_vector_type(8)));
typedef unsigned short u16;

__device__ __forceinline__ u16 f2bf(float f) {
    union { float f; unsigned u; } v; v.f = f;
    return (u16)((v.u + 0x7fffu + ((v.u >> 16) & 1u)) >> 16);
}
__device__ __forceinline__ float bf2f(u16 h) {
    union { unsigned u; float f; } v; v.u = ((unsigned)h) << 16;
    return v.f;
}
__device__ __forceinline__ float fast_exp2(float x) {
#if __has_builtin(__builtin_amdgcn_exp2f)
    return __builtin_amdgcn_exp2f(x);
#else
    return exp2f(x);
#endif
}

// async global->LDS, 16B/lane; LDS dest = wave-uniform base + lane*16 [m97/m104]
__device__ __forceinline__ void gload_lds16(const void* g, void* l) {
    __builtin_amdgcn_global_load_lds((__attribute__((address_space(1))) void*)g,
                                     (__attribute__((address_space(3))) void*)l, 16, 0, 0);
}

// Mega convert: x (1048576 units) -> xb, then wq|wk|wv (524288+131072+131072) -> wqkvb
// contiguous. 1 unit = 8 elems. Grid exactly 7168 blocks x 256.
__global__ __launch_bounds__(256) void cvt_all(const float* __restrict__ x,  const float* __restrict__ wq,
                                               const float* __restrict__ wk, const float* __restrict__ wv,
                                               u16* __restrict__ xb, u16* __restrict__ wqkvb) {
    int u = blockIdx.x * 256 + threadIdx.x;
    const float* src;
    u16* dst;
    if (u < 1048576) { src = x + (size_t)u * 8; dst = xb + (size_t)u * 8; }
    else {
        int w = u - 1048576;
        dst = wqkvb + (size_t)w * 8;
        if (w < 524288)      src = wq + (size_t)w * 8;
        else if (w < 655360) src = wk + (size_t)(w - 524288) * 8;
        else                 src = wv + (size_t)(w - 655360) * 8;
    }
    const float4* p = (const float4*)src;
    float4 a = p[0], b = p[1];
    s16x8 o;
    o[0] = f2bf(a.x); o[1] = f2bf(a.y); o[2] = f2bf(a.z); o[3] = f2bf(a.w);
    o[4] = f2bf(b.x); o[5] = f2bf(b.y); o[6] = f2bf(b.z); o[7] = f2bf(b.w);
    *(s16x8*)dst = o;
}

// fp32 -> bf16 elementwise (for wo after wqkv region is free)
__global__ __launch_bounds__(256) void cvt_kernel(const float* __restrict__ in,
                                                  u16* __restrict__ out, int n8) {
    int i = blockIdx.x * 256 + threadIdx.x;
    if (i >= n8) return;
    const float4* p = (const float4*)(in + (size_t)i * 8);
    float4 a = p[0], b = p[1];
    s16x8 o;
    o[0] = f2bf(a.x); o[1] = f2bf(a.y); o[2] = f2bf(a.z); o[3] = f2bf(a.w);
    o[4] = f2bf(b.x); o[5] = f2bf(b.y); o[6] = f2bf(b.z); o[7] = f2bf(b.w);
    *(s16x8*)(out + (size_t)i * 8) = o;
}

// combine split halves: ab[...] = (O0+O1)/(L0+L1), for qt in [96,128).
// i indexes (g,qti,row,colblk): 8*32*16*64 = 262144 threads.
__global__ __launch_bounds__(256) void norm_comb(const float* __restrict__ Oacc,
                                                 const float* __restrict__ Lacc,
                                                 u16* __restrict__ ab) {
    int i = blockIdx.x * 256 + threadIdx.x;
    int g = i >> 15;
    int rem = i & 32767;
    int qti = rem >> 10;
    int rem2 = rem & 1023;
    int row = rem2 >> 6;
    int colblk = rem2 & 63;
    int col0 = colblk * 8;
    int head = colblk >> 4;                 // head within group (col0>>7)
    size_t tile0 = (size_t)(g * 32 + qti);
    size_t tile1 = (size_t)((8 + g) * 32 + qti);
    const float* p0 = Oacc + tile0 * 8192 + row * 512 + col0;
    const float* p1 = Oacc + tile1 * 8192 + row * 512 + col0;
    float L0 = Lacc[(tile0 * 4 + head) * 16 + row];
    float L1 = Lacc[(tile1 * 4 + head) * 16 + row];
    float inv = 1.0f / (L0 + L1);
    int b = g >> 2, kv = g & 3;
    int token = (96 + qti) * 16 + row;
    u16* pd = ab + ((size_t)(b * 2048 + token) << 11) + kv * 512 + col0;
    float4 a0 = ((const float4*)p0)[0], a1 = ((const float4*)p0)[1];
    float4 b0 = ((const float4*)p1)[0], b1 = ((const float4*)p1)[1];
    s16x8 o;
    o[0] = f2bf((a0.x + b0.x) * inv); o[1] = f2bf((a0.y + b0.y) * inv);
    o[2] = f2bf((a0.z + b0.z) * inv); o[3] = f2bf((a0.w + b0.w) * inv);
    o[4] = f2bf((a1.x + b1.x) * inv); o[5] = f2bf((a1.y + b1.y) * inv);
    o[6] = f2bf((a1.z + b1.z) * inv); o[7] = f2bf((a1.w + b1.w) * inv);
    *(s16x8*)pd = o;
}

// C = A[M,K] @ B[N,K]^T, bf16 in. 128x128 tile, BK=64, global_load_lds staging,
// XOR-swizzled LDS. OUT=1: fp32 C[M,N]. OUT=4: fused qkv routing:
//   n<2048 -> bf16 Cq[m*2048+n]; 2048<=n<2560 -> bf16 Ck[m*512+(n-2048)];
//   n>=2560 -> bf16 transposed Cv[(n-2560)*M + m]
template<int OUT>
__global__ __launch_bounds__(256) void gemm128(const u16* __restrict__ A, const u16* __restrict__ B,
                                               void* __restrict__ C, void* __restrict__ Ck,
                                               void* __restrict__ Cv, int M, int N, int K) {
    __shared__ __align__(16) u16 Ald[128 * 64];
    __shared__ __align__(16) u16 Bld[128 * 64];
    const int t = threadIdx.x, wid = t >> 6, lane = t & 63;
    const int m0 = blockIdx.y * 128, n0 = blockIdx.x * 128;
    const int ml = lane & 15, quad = lane >> 4, m7 = ml & 7;
    const int wm = (wid & 1) * 64, wn = (wid >> 1) * 64;
    const int sr = lane >> 3, sc = lane & 7;

    f32x4 acc[4][4] = {};

    for (int k0 = 0; k0 < K; k0 += 64) {
        if (k0) __syncthreads();
        #pragma unroll
        for (int i = 0; i < 4; ++i) {
            int seg = wid * 4 + i;
            int r = seg * 8 + sr;
            int c = (sc ^ (r & 7)) * 8;
            gload_lds16(A + (size_t)(m0 + r) * K + k0 + c, &Ald[seg * 512]);
            gload_lds16(B + (size_t)(n0 + r) * K + k0 + c, &Bld[seg * 512]);
        }
        __syncthreads();
        #pragma unroll
        for (int kk = 0; kk < 64; kk += 32) {
            s16x8 af[4], bf[4];
            #pragma unroll
            for (int mi = 0; mi < 4; ++mi)
                af[mi] = *(const s16x8*)&Ald[(wm + mi * 16 + ml) * 64 + (((kk >> 3) + quad) ^ m7) * 8];
            #pragma unroll
            for (int ni = 0; ni < 4; ++ni)
                bf[ni] = *(const s16x8*)&Bld[(wn + ni * 16 + ml) * 64 + (((kk >> 3) + quad) ^ m7) * 8];
            #pragma unroll
            for (int mi = 0; mi < 4; ++mi)
                #pragma unroll
                for (int ni = 0; ni < 4; ++ni)
                    acc[mi][ni] = __builtin_amdgcn_mfma_f32_16x16x32_bf16(af[mi], bf[ni], acc[mi][ni], 0, 0, 0);
        }
    }
    // C/D layout: col=lane&15, row=quad*4+reg [m89/m91]
    #pragma unroll
    for (int mi = 0; mi < 4; ++mi)
        #pragma unroll
        for (int ni = 0; ni < 4; ++ni) {
            int gmb = m0 + wm + mi * 16 + quad * 4;
            int gn  = n0 + wn + ni * 16 + ml;
            if constexpr (OUT == 4) {
                if (n0 < 2048) {
                    #pragma unroll
                    for (int r = 0; r < 4; ++r)
                        ((u16*)C)[(size_t)(gmb + r) * 2048 + gn] = f2bf(acc[mi][ni][r]);
                } else if (n0 < 2560) {
                    #pragma unroll
                    for (int r = 0; r < 4; ++r)
                        ((u16*)Ck)[(size_t)(gmb + r) * 512 + (gn - 2048)] = f2bf(acc[mi][ni][r]);
                } else {
                    ushort4 v;
                    v.x = f2bf(acc[mi][ni][0]); v.y = f2bf(acc[mi][ni][1]);
                    v.z = f2bf(acc[mi][ni][2]); v.w = f2bf(acc[mi][ni][3]);
                    *(ushort4*)((u16*)Cv + (size_t)(gn - 2560) * M + gmb) = v;
                }
            } else {
                #pragma unroll
                for (int r = 0; r < 4; ++r)
                    ((float*)C)[(size_t)(gmb + r) * N + gn] = acc[mi][ni][r];
            }
        }
}

// Fused NeoX RoPE for q (16 heads, scaled) + k (4 heads). pos = tok % 2048.
// q pre-scaled by 1/sqrt(128)*log2(e) -> attention works in the log2 domain.
__global__ __launch_bounds__(256) void rope_kernel(u16* __restrict__ qb, u16* __restrict__ kb,
                                                   int nq, int ntot, float sq) {
    int idx = blockIdx.x * 256 + threadIdx.x;
    if (idx >= ntot) return;
    u16* base; int nheads; float scl; int id;
    if (idx < nq) { base = qb; nheads = 16; scl = sq;  id = idx; }
    else          { base = kb; nheads = 4;  scl = 1.f; id = idx - nq; }
    int i = id & 63;
    int rest = id >> 6;
    int hh = rest % nheads;
    int tok = rest / nheads;
    int tpos = tok & 2047;
    u16* row = base + (size_t)tok * nheads * 128 + hh * 128;
    float x1 = bf2f(row[i]);
    float x2 = bf2f(row[i + 64]);
    float inv = expf(-(float)i * 0.14391156731570787f); // 10000^(-i/64)
    float ang = (float)tpos * inv;
    float s, c;
    sincosf(ang, &s, &c);
    row[i]      = f2bf((x1 * c - x2 * s) * scl);
    row[i + 64] = f2bf((x2 * c + x1 * s) * scl);
}

// ---------- v3 attention (fallback when workspace too small) ----------
__global__ __launch_bounds__(256, 4) void attn_kernel(const u16* __restrict__ Q, const u16* __restrict__ Kb,
                                                      const u16* __restrict__ Vt, u16* __restrict__ O) {
    __shared__ __align__(16) u16 Klds[64 * 128];   // 16KB
    __shared__ __align__(16) u16 Vlds[128 * 64];   // 16KB
    __shared__ __align__(16) u16 Plds[4][16 * 64]; // 8KB
    const int t = threadIdx.x, wslot = t >> 6, lane = t & 63;
    const int kv = blockIdx.y, b = blockIdx.z;
    const int g = kv + 4 * b;
    const int bx = blockIdx.x;
    int qt;
    switch ((g >> 1) & 3) {
        case 0:  qt = bx; break;
        case 1:  qt = 127 - bx; break;
        case 2:  qt = (bx + 64) & 127; break;
        default: qt = (63 - bx) & 127; break;
    }
    const int h = kv * 4 + wslot;
    const int ml = lane & 15, quad = lane >> 4, m7 = ml & 7;
    const int t0 = qt * 16;
    const int n = (qt >> 2) + 1;

    s16x8 qf[4];
    {
        const u16* qp = Q + ((size_t)(b * 2048 + t0 + ml) * 2048 + h * 128);
        #pragma unroll
        for (int kc = 0; kc < 4; ++kc)
            qf[kc] = *(const s16x8*)(qp + kc * 32 + quad * 8);
    }

    s16x8 ones;
    #pragma unroll
    for (int j = 0; j < 8; ++j) ones[j] = (short)0x3F80;

    f32x4 Oa[8] = {};
    f32x4 L = {};

    for (int it = 0; it < n; ++it) {
        const int s0 = it * 64;
        if (it) __syncthreads();
        #pragma unroll
        for (int i = 0; i < 4; ++i) {
            int seg = wslot * 4 + i;
            int kr = seg * 4 + (lane >> 4);
            int kc = ((lane & 15) ^ (kr & 7)) * 8;
            gload_lds16(Kb + (size_t)(b * 2048 + s0 + kr) * 512 + kv * 128 + kc, &Klds[seg * 512]);
            int vr = seg * 8 + (lane >> 3);
            int vc = ((lane & 7) ^ (vr & 7)) * 8;
            gload_lds16(Vt + (size_t)(kv * 128 + vr) * 4096 + b * 2048 + s0 + vc, &Vlds[seg * 512]);
        }
        __syncthreads();

        f32x4 S[4] = {};
        #pragma unroll
        for (int kc = 0; kc < 4; ++kc)
            #pragma unroll
            for (int ti = 0; ti < 4; ++ti) {
                s16x8 kf = *(const s16x8*)&Klds[(ti * 16 + ml) * 128 + ((kc * 4 + quad) ^ m7) * 8];
                S[ti] = __builtin_amdgcn_mfma_f32_16x16x32_bf16(qf[kc], kf, S[ti], 0, 0, 0);
            }

        {
            u16* pl = &Plds[wslot][0];
            const bool diag = (it == n - 1);
            #pragma unroll
            for (int r = 0; r < 4; ++r) {
                int qr = t0 + quad * 4 + r;
                int row = quad * 4 + r;
                #pragma unroll
                for (int ti = 0; ti < 4; ++ti) {
                    float e = fast_exp2(S[ti][r]);
                    if (diag && (s0 + ti * 16 + ml > qr)) e = 0.f;
                    union { float f; unsigned u; } cv; cv.f = e;
                    pl[row * 64 + (((ti * 2 + (ml >> 3)) ^ (row & 7)) * 8) + (ml & 7)] = (u16)(cv.u >> 16);
                }
            }
        }
        asm volatile("s_waitcnt lgkmcnt(0)" ::: "memory");
        s16x8 pf[2];
        pf[0] = *(const s16x8*)&Plds[wslot][ml * 64 + ((quad)     ^ m7) * 8];
        pf[1] = *(const s16x8*)&Plds[wslot][ml * 64 + ((4 + quad) ^ m7) * 8];
        asm volatile("s_waitcnt lgkmcnt(0)" ::: "memory");

        #pragma unroll
        for (int c = 0; c < 2; ++c) {
            #pragma unroll
            for (int nt = 0; nt < 8; ++nt) {
                s16x8 vf = *(const s16x8*)&Vlds[(nt * 16 + ml) * 64 + ((c * 4 + quad) ^ m7) * 8];
                Oa[nt] = __builtin_amdgcn_mfma_f32_16x16x32_bf16(pf[c], vf, Oa[nt], 0, 0, 0);
            }
            L = __builtin_amdgcn_mfma_f32_16x16x32_bf16(pf[c], ones, L, 0, 0, 0);
        }
    }

    #pragma unroll
    for (int nt = 0; nt < 8; ++nt)
        #pragma unroll
        for (int r = 0; r < 4; ++r) {
            int col = h * 128 + nt * 16 + ml;
            O[(size_t)(b * 2048 + t0 + quad * 4 + r) * 2048 + col] = f2bf(Oa[nt][r] / L[r]);
        }
}

// ---------- v9 attention: critical-path-capped scheduling ----------
// Evidence: v3 = 109.6us = 32 iters x 8.2Kcyc = the single longest block (the
// critical path IS the wall). v6's atomic split kept occupancy gains but
// inflated T_iter (atomic epilogue, 6 blocks/CU queue). v9 keeps v3's exact
// iteration body (T_iter 8.2K, 64 VGPR, 40KB LDS, 4 blocks/CU) and only caps
// block length: qt>=96 split into two KV-halves writing disjoint f32 partial
// buffers with PLAIN stores (no atomics, no zero-init: each half covers every
// element exactly once); norm_comb computes (O0+O1)/(L0+L1). Max block = 24
// iters (qt 64..95 unsplit). 1280 blocks, longest-first, groups interleaved
// across XCDs (no pinning). Concurrency bound sum/max = 66/24 = 2.75.
__global__ __launch_bounds__(256, 4) void attn_sched(const u16* __restrict__ Q, const u16* __restrict__ Kb,
                                                     const u16* __restrict__ Vt, u16* __restrict__ O,
                                                     float* __restrict__ Oacc, float* __restrict__ Lacc) {
    __shared__ __align__(16) u16 Klds[64 * 128];   // 16KB
    __shared__ __align__(16) u16 Vlds[128 * 64];   // 16KB
    __shared__ __align__(16) u16 Plds[4][16 * 64]; // 8KB
    const int t = threadIdx.x, wslot = t >> 6, lane = t & 63;
    const int bid = blockIdx.x;          // 1280 blocks
    const int idx = bid >> 3, g = bid & 7;
    const int kv = g & 3, b = g >> 2;

    // work list, length-descending: idx 0..31: qt 95..64 full (24..17 iters);
    // idx 32..95: halves of qt 127..96 (<=16); idx 96..159: qt 63..0 (16..1).
    int qt, it0, it1, nfull, hsel = 0;
    bool partial;
    if (idx < 32) {
        qt = 95 - idx; nfull = (qt >> 2) + 1; it0 = 0; it1 = nfull; partial = false;
    } else if (idx < 96) {
        int p = (idx - 32) >> 1; hsel = (idx - 32) & 1;
        qt = 127 - p; nfull = (qt >> 2) + 1;
        int nh = nfull >> 1;
        it0 = hsel ? nh : 0;
        it1 = hsel ? nfull : nh;
        partial = true;
    } else {
        qt = 159 - idx; nfull = (qt >> 2) + 1; it0 = 0; it1 = nfull; partial = false;
    }

    const int h = kv * 4 + wslot;
    const int ml = lane & 15, quad = lane >> 4, m7 = ml & 7;
    const int t0 = qt * 16;

    // Q fragments: A layout m=lane&15, k=quad*8+j [m120]
    s16x8 qf[4];
    {
        const u16* qp = Q + ((size_t)(b * 2048 + t0 + ml) * 2048 + h * 128);
        #pragma unroll
        for (int kc = 0; kc < 4; ++kc)
            qf[kc] = *(const s16x8*)(qp + kc * 32 + quad * 8);
    }

    s16x8 ones;
    #pragma unroll
    for (int j = 0; j < 8; ++j) ones[j] = (short)0x3F80; // bf16 1.0

    f32x4 Oa[8] = {};
    f32x4 L = {};

    for (int it = it0; it < it1; ++it) {
        const int s0 = it * 64;
        if (it != it0) __syncthreads(); // all waves done reading previous K/V tile
        #pragma unroll
        for (int i = 0; i < 4; ++i) {
            int seg = wslot * 4 + i;
            int kr = seg * 4 + (lane >> 4);
            int kc = ((lane & 15) ^ (kr & 7)) * 8;
            gload_lds16(Kb + (size_t)(b * 2048 + s0 + kr) * 512 + kv * 128 + kc, &Klds[seg * 512]);
            int vr = seg * 8 + (lane >> 3);
            int vc = ((lane & 7) ^ (vr & 7)) * 8;
            gload_lds16(Vt + (size_t)(kv * 128 + vr) * 4096 + b * 2048 + s0 + vc, &Vlds[seg * 512]);
        }
        __syncthreads(); // staging drained (vmcnt0)

        // QK^T
        f32x4 S[4] = {};
        #pragma unroll
        for (int kc = 0; kc < 4; ++kc)
            #pragma unroll
            for (int ti = 0; ti < 4; ++ti) {
                s16x8 kf = *(const s16x8*)&Klds[(ti * 16 + ml) * 128 + ((kc * 4 + quad) ^ m7) * 8];
                S[ti] = __builtin_amdgcn_mfma_f32_16x16x32_bf16(qf[kc], kf, S[ti], 0, 0, 0);
            }

        // softmax (no max-shift): p = exp2(s); causal mask only on diagonal tile
        // (h0 halves never reach it == nfull-1)
        {
            u16* pl = &Plds[wslot][0];
            const bool diag = (it == nfull - 1);
            #pragma unroll
            for (int r = 0; r < 4; ++r) {
                int qr = t0 + quad * 4 + r;
                int row = quad * 4 + r;
                #pragma unroll
                for (int ti = 0; ti < 4; ++ti) {
                    float e = fast_exp2(S[ti][r]);
                    if (diag && (s0 + ti * 16 + ml > qr)) e = 0.f;
                    union { float f; unsigned u; } cv; cv.f = e;
                    pl[row * 64 + (((ti * 2 + (ml >> 3)) ^ (row & 7)) * 8) + (ml & 7)] = (u16)(cv.u >> 16);
                }
            }
        }
        asm volatile("s_waitcnt lgkmcnt(0)" ::: "memory");
        s16x8 pf[2];
        pf[0] = *(const s16x8*)&Plds[wslot][ml * 64 + ((quad)     ^ m7) * 8];
        pf[1] = *(const s16x8*)&Plds[wslot][ml * 64 + ((4 + quad) ^ m7) * 8];
        asm volatile("s_waitcnt lgkmcnt(0)" ::: "memory");

        // PV + l
        #pragma unroll
        for (int c = 0; c < 2; ++c) {
            #pragma unroll
            for (int nt = 0; nt < 8; ++nt) {
                s16x8 vf = *(const s16x8*)&Vlds[(nt * 16 + ml) * 64 + ((c * 4 + quad) ^ m7) * 8];
                Oa[nt] = __builtin_amdgcn_mfma_f32_16x16x32_bf16(pf[c], vf, Oa[nt], 0, 0, 0);
            }
            L = __builtin_amdgcn_mfma_f32_16x16x32_bf16(pf[c], ones, L, 0, 0, 0);
        }
    }

    if (!partial) {
        #pragma unroll
        for (int nt = 0; nt < 8; ++nt)
            #pragma unroll
            for (int r = 0; r < 4; ++r) {
                int col = h * 128 + nt * 16 + ml;
                O[(size_t)(b * 2048 + t0 + quad * 4 + r) * 2048 + col] = f2bf(Oa[nt][r] / L[r]);
            }
    } else {
        // plain f32 partial stores (disjoint per half; full coverage -> no zeroing)
        const int qti = qt - 96;
        float* Ob = Oacc + (size_t)((hsel * 8 + g) * 32 + qti) * 8192;
        #pragma unroll
        for (int nt = 0; nt < 8; ++nt)
            #pragma unroll
            for (int r = 0; r < 4; ++r)
                Ob[(quad * 4 + r) * 512 + wslot * 128 + nt * 16 + ml] = Oa[nt][r];
        if (ml == 0) {
            float* Lb = Lacc + ((size_t)((hsel * 8 + g) * 32 + qti) * 4 + wslot) * 16;
            #pragma unroll
            for (int r = 0; r < 4; ++r)
                Lb[quad * 4 + r] = L[r];
        }
    }
}

extern "C" void kernel_launch(void* const* d_in, const int* in_sizes, int n_in,
                              void* d_out, int out_size, void* d_ws, size_t ws_size,
                              hipStream_t stream) {
    const float* x  = (const float*)d_in[0];
    const float* wq = (const float*)d_in[1];
    const float* wk = (const float*)d_in[2];
    const float* wv = (const float*)d_in[3];
    const float* wo = (const float*)d_in[4];
    float* out = (float*)d_out;
    char* ws = (char*)d_ws;

    const size_t MB = 1024 * 1024;
    // ws: [0,16M) xb (reused as ab) | [16M,32M) qb | [32M,36M) kb |
    //     [36M,40M) vtb | [40M,52M) wqkvb (reused as wob) |
    //     [52M,68M) Opart f32 (2 halves x 8MB) | [68M,68.25M) Lpart f32
    u16* xb    = (u16*)(ws);
    u16* qb    = (u16*)(ws + 16 * MB);
    u16* kb    = (u16*)(ws + 32 * MB);
    u16* vtb   = (u16*)(ws + 36 * MB);
    u16* wqkvb = (u16*)(ws + 40 * MB);
    u16* ab    = xb;    // attn output over xb (x last read by qkv GEMM)
    u16* wob   = wqkvb; // wo bf16 over wqkvb (last read by qkv GEMM)

    const bool split = ws_size >= 70 * MB; // proven true in r6

    cvt_all<<<7168, 256, 0, stream>>>(x, wq, wk, wv, xb, wqkvb);

    gemm128<4><<<dim3(24, 32), 256, 0, stream>>>(xb, wqkvb, qb, kb, vtb, 4096, 3072, 2048);

    cvt_kernel<<<2048, 256, 0, stream>>>(wo, wob, 524288); // wqkvb region now free

    // q pre-scaled by 1/sqrt(128)*log2(e)
    rope_kernel<<<20480, 256, 0, stream>>>(qb, kb, 4194304, 5242880, 0.12751743f);

    if (split) {
        float* Oacc = (float*)(ws + 52 * MB);
        float* Lacc = (float*)(ws + 68 * MB);
        attn_sched<<<1280, 256, 0, stream>>>(qb, kb, vtb, ab, Oacc, Lacc);
        norm_comb<<<1024, 256, 0, stream>>>(Oacc, Lacc, ab);
    } else {
        attn_kernel<<<dim3(128, 4, 2), 256, 0, stream>>>(qb, kb, vtb, ab);
    }

    gemm128<1><<<dim3(16, 32), 256, 0, stream>>>(ab, wob, out, nullptr, nullptr, 4096, 2048, 2048);
}